// Round 1
// baseline (194.463 us; speedup 1.0000x reference)
//
#include <hip/hip_runtime.h>
#include <hip/hip_bf16.h>

// BEV bilinear feature extraction.
// feats: (B=4, C=256, H=188, W=188) f32
// centers: (B=4, N=500, 3) f32
// out: (B, N, C) f32
//
// v2: two points per block (grid halved to 1000). Each thread gathers the
// 4 bilinear corners for its channel for BOTH points (8 independent global
// loads in flight) before any dependent math — doubles memory-level
// parallelism per wave to hide the uncoalesced-gather latency (channel
// stride H*W*4 B makes every lane's load a distinct cache line; inherent
// to the (B,C,H,W) layout). Two coalesced 1 KiB row stores per block.

constexpr int B = 4;
constexpr int C = 256;
constexpr int H = 188;
constexpr int W = 188;
constexpr int N = 500;

__global__ __launch_bounds__(256) void bev_extract_kernel(
    const float* __restrict__ feats,
    const float* __restrict__ centers,
    float* __restrict__ out)
{
    const int c   = threadIdx.x;        // 0 .. 255 (channel)
    const int pt0 = blockIdx.x * 2;     // 0 .. B*N-2
    const int pt1 = pt0 + 1;

    // ---- point 0 coords (uniform across block; scalar-pipe friendly) ----
    const int b0 = pt0 / N;
    const int n0 = pt0 - b0 * N;
    const float cx0 = centers[(b0 * N + n0) * 3 + 0];
    const float cy0 = centers[(b0 * N + n0) * 3 + 1];
    // Match reference numerics: (c - PC_START) / VOXEL / OUT_STRIDE
    const float xA = (cx0 - (-75.2f)) / 0.1f / 8.0f;
    const float yA = (cy0 - (-75.2f)) / 0.1f / 8.0f;

    // ---- point 1 coords ----
    const int b1 = pt1 / N;
    const int n1 = pt1 - b1 * N;
    const float cx1 = centers[(b1 * N + n1) * 3 + 0];
    const float cy1 = centers[(b1 * N + n1) * 3 + 1];
    const float xB = (cx1 - (-75.2f)) / 0.1f / 8.0f;
    const float yB = (cy1 - (-75.2f)) / 0.1f / 8.0f;

    // ---- clamp BEFORE weight computation (torch/reference semantics) ----
    const int xfA = (int)floorf(xA);
    const int yfA = (int)floorf(yA);
    const int x0A = min(max(xfA,     0), W - 1);
    const int x1A = min(max(xfA + 1, 0), W - 1);
    const int y0A = min(max(yfA,     0), H - 1);
    const int y1A = min(max(yfA + 1, 0), H - 1);

    const int xfB = (int)floorf(xB);
    const int yfB = (int)floorf(yB);
    const int x0B = min(max(xfB,     0), W - 1);
    const int x1B = min(max(xfB + 1, 0), W - 1);
    const int y0B = min(max(yfB,     0), H - 1);
    const int y1B = min(max(yfB + 1, 0), H - 1);

    // Per-point spatial offsets (uniform per block → SGPR adds).
    const int offA_a = y0A * W + x0A;
    const int offA_b = y1A * W + x0A;
    const int offA_c = y0A * W + x1A;
    const int offA_d = y1A * W + x1A;

    const int offB_a = y0B * W + x0B;
    const int offB_b = y1B * W + x0B;
    const int offB_c = y0B * W + x1B;
    const int offB_d = y1B * W + x1B;

    const float* baseA = feats + (size_t)(b0 * C + c) * (H * W);
    const float* baseB = feats + (size_t)(b1 * C + c) * (H * W);

    // ---- issue all 8 gathers before any dependent math ----
    const float IaA = baseA[offA_a];
    const float IbA = baseA[offA_b];
    const float IcA = baseA[offA_c];
    const float IdA = baseA[offA_d];
    const float IaB = baseB[offB_a];
    const float IbB = baseB[offB_b];
    const float IcB = baseB[offB_c];
    const float IdB = baseB[offB_d];

    // ---- weights ----
    const float x0fA = (float)x0A, x1fA = (float)x1A;
    const float y0fA = (float)y0A, y1fA = (float)y1A;
    const float waA = (x1fA - xA) * (y1fA - yA);
    const float wbA = (x1fA - xA) * (yA  - y0fA);
    const float wcA = (xA  - x0fA) * (y1fA - yA);
    const float wdA = (xA  - x0fA) * (yA  - y0fA);

    const float x0fB = (float)x0B, x1fB = (float)x1B;
    const float y0fB = (float)y0B, y1fB = (float)y1B;
    const float waB = (x1fB - xB) * (y1fB - yB);
    const float wbB = (x1fB - xB) * (yB  - y0fB);
    const float wcB = (xB  - x0fB) * (y1fB - yB);
    const float wdB = (xB  - x0fB) * (yB  - y0fB);

    out[(size_t)pt0 * C + c] = IaA * waA + IbA * wbA + IcA * wcA + IdA * wdA;
    out[(size_t)pt1 * C + c] = IaB * waB + IbB * wbB + IcB * wcB + IdB * wdB;
}

extern "C" void kernel_launch(void* const* d_in, const int* in_sizes, int n_in,
                              void* d_out, int out_size, void* d_ws, size_t ws_size,
                              hipStream_t stream)
{
    const float* feats   = (const float*)d_in[0];  // (B, C, H, W)
    const float* centers = (const float*)d_in[1];  // (B, N, 3)
    float* out = (float*)d_out;                    // (B, N, C)

    dim3 grid((B * N) / 2);   // 1000 blocks, 2 points each
    dim3 block(C);            // one thread per channel
    bev_extract_kernel<<<grid, block, 0, stream>>>(feats, centers, out);
}